// Round 9
// baseline (1007.566 us; speedup 1.0000x reference)
//
#include <hip/hip_runtime.h>
#include <hip/hip_bf16.h>
#include <math.h>

// ---------------------------------------------------------------------------
// Round 9: (a) BM=64 GEMM variant for the grid-starved GEMMs (qkv/proj/mlp
// were 256-384 blocks = 1-1.5 block/CU; now 512-768 = 2-3/CU); (b) A-tile
// XOR swizzle (row&3)<<4 (64B rows permit a 2-bit involution; 8-way -> 4-way
// read conflict), inverse folded into the global_load_lds source slot;
// (c) s_setprio(1) around attention MFMA clusters (T5, m191).
// Math/layout of B-split, epilogues, attention: unchanged from round 8
// (verified 995 us, absmax 0.015625).
//   B=1, T=2048, C=2048, H=32, G=8, HS=64, FF=5632, LEVELS=63
// ---------------------------------------------------------------------------

#define T_SEQ 2048
#define C_DIM 2048
#define QKV_DIM 3072
#define FF_DIM 5632
#define LOG2E 1.44269504088896340736f

typedef short bf16x8 __attribute__((ext_vector_type(8)));
typedef float f32x4 __attribute__((ext_vector_type(4)));
typedef unsigned int u32x4 __attribute__((ext_vector_type(4)));
typedef unsigned short u16;
typedef unsigned int u32;

__device__ __forceinline__ u16 f2bf(float f) {
  __hip_bfloat16 h = __float2bfloat16(f);   // RNE
  return *reinterpret_cast<u16*>(&h);
}
__device__ __forceinline__ float bf2f(u16 u) {
  __hip_bfloat16 h;
  *reinterpret_cast<u16*>(&h) = u;
  return __bfloat162float(h);
}

__device__ __forceinline__ float qint(float v, float alpha) {
  float xd = fmaxf(v, 0.0f) / alpha;
  xd = fminf(xd, 1.0f);
  return rintf(xd * 63.0f);
}

// hardware 2^x (TRANS pipe, 1 instr).  exp2(-inf)=0.
__device__ __forceinline__ float exp2_hw(float x) {
  float r;
  asm("v_exp_f32 %0, %1" : "=v"(r) : "v"(x));
  return r;
}
// pack two f32 -> two bf16 (RNE); lo -> bits[15:0], hi -> [31:16]
__device__ __forceinline__ u32 cvtpk_bf16(float lo, float hi) {
  u32 r;
  asm("v_cvt_pk_bf16_f32 %0, %1, %2" : "=v"(r) : "v"(lo), "v"(hi));
  return r;
}

__device__ __forceinline__ void llds16(const void* g, void* l) {
  __builtin_amdgcn_global_load_lds(
      (const __attribute__((address_space(1))) unsigned int*)g,
      (__attribute__((address_space(3))) unsigned int*)l, 16, 0, 0);
}

// ---------------------------------------------------------------------------
// RMSNorm + quant -> integer levels stored as bf16 (exact).
// ---------------------------------------------------------------------------
__global__ __launch_bounds__(256) void rmsnorm_quant_int(const float* __restrict__ x,
                                                         const float* __restrict__ w,
                                                         const float* __restrict__ alpha_p,
                                                         u16* __restrict__ out) {
  const int row = blockIdx.x;
  const float* xr = x + (size_t)row * C_DIM;
  const int base = threadIdx.x * 8;
  float4 v0 = *reinterpret_cast<const float4*>(xr + base);
  float4 v1 = *reinterpret_cast<const float4*>(xr + base + 4);
  float xv[8] = {v0.x, v0.y, v0.z, v0.w, v1.x, v1.y, v1.z, v1.w};
  float ss = 0.0f;
#pragma unroll
  for (int k = 0; k < 8; ++k) ss = fmaf(xv[k], xv[k], ss);
#pragma unroll
  for (int m = 1; m < 64; m <<= 1) ss += __shfl_xor(ss, m);
  __shared__ float wsum[4];
  const int lane = threadIdx.x & 63, wv = threadIdx.x >> 6;
  if (lane == 0) wsum[wv] = ss;
  __syncthreads();
  const float tot = wsum[0] + wsum[1] + wsum[2] + wsum[3];
  const float rs = 1.0f / sqrtf(tot * (1.0f / 2048.0f) + 1e-5f);
  const float alpha = *alpha_p;
  u16 ov[8];
#pragma unroll
  for (int k = 0; k < 8; ++k) ov[k] = f2bf(qint((w[base + k] * xv[k]) * rs, alpha));
  u16* orow = out + (size_t)row * C_DIM + base;
#pragma unroll
  for (int k = 0; k < 2; ++k) {
    ushort4 u;
    u.x = ov[k * 4]; u.y = ov[k * 4 + 1]; u.z = ov[k * 4 + 2]; u.w = ov[k * 4 + 3];
    *reinterpret_cast<ushort4*>(orow + k * 4) = u;
  }
}

// ---------------------------------------------------------------------------
// Multi-term bf16 MFMA GEMM, double-buffered, in-register B-split from fp32.
//   C[m,n] = sum_k A_terms . (Bhi + Blo)[n,k],  Bhi=trunc16(B), Blo=RNE(B-Bhi)
// MODE 2: (A0,Bhi)+(A0,Blo).   MODE 3: (A0,Bhi)+(A1,Bhi)+(A0,Blo).
// BM: 128 (wave tile 64x64) or 64 (wave tile 32x64, for small grids).
// A planes [BM][32]bf16 XOR-swizzled (row&3)<<4; B [128][32]f32 XOR-swizzled
// (row&7)<<4 -- both via pre-permuted global_load_lds source slots.
// EPI 0: Cf = aux + acc;  EPI 1: quant levels;  EPI 2: split planes;
// EPI 3: gu = silu(g)*acc -> split planes (in place).
// ---------------------------------------------------------------------------
template <int MODE, int EPI, int BM>
__global__ __launch_bounds__(256) void gemm_mfma(
    const u16* __restrict__ A0, const u16* __restrict__ A1,
    const float* __restrict__ Bf,
    float* __restrict__ Cf, u16* __restrict__ Cq, const float* __restrict__ auxf,
    u16* __restrict__ p_hi, u16* __restrict__ p_lo,
    const float* __restrict__ sA_p, const float* __restrict__ aQ_p,
    int M, int N, int K) {
  constexpr int APL  = BM * 64;                    // bytes per A plane (BMx32 bf16)
  constexpr int BOFF = (MODE == 3 ? 2 : 1) * APL;  // B tile offset
  constexpr int BUFB = BOFF + 16384;               // buffer size
  constexpr int WRT  = BM / 2;                     // rows per wave (M)
  constexpr int MF   = WRT / 16;                   // M fragments per wave
  __shared__ __align__(16) char lds[2 * BUFB];

  const int tid = threadIdx.x;
  const int nwg = gridDim.x * gridDim.y;
  const int wg = blockIdx.y * gridDim.x + blockIdx.x;
  const int swz = (wg & 7) * (nwg >> 3) + (wg >> 3);
  const int bx = swz % gridDim.x, by = swz / gridDim.x;
  const int row0 = by * BM, col0 = bx * 128;

  const int w = tid >> 6, lane = tid & 63;
  const int wr = w >> 1, wc = w & 1;
  const int fr = lane & 15, gq = lane >> 4;

  // A staging: chunk cA = w*BM + lane (+64 when BM=128); row = cA>>2,
  // source slot pre-permuted with the read-side XOR (row&3).
  const int cA = w * BM + lane;
  const int rA = cA >> 2;
  const int sAsw = ((cA & 3) ^ (rA & 3)) * 8;      // elements
  // B staging: 1024 chunks of 16B; chunk = it*256+tid
  const int rB = tid >> 3;
  const int sB0 = tid & 7;

  char* cu = lds;
  char* nx = lds + BUFB;

  auto stage = [&](char* base, int kt) {
    {
      const u16* g0 = A0 + (size_t)(row0 + rA) * K + kt + sAsw;
      llds16(g0, base + (w * BM) * 16);
      if constexpr (BM == 128) {
        const u16* g1 = A0 + (size_t)(row0 + rA + 16) * K + kt + sAsw;
        llds16(g1, base + (w * BM + 64) * 16);
      }
    }
    if constexpr (MODE == 3) {
      const u16* g0 = A1 + (size_t)(row0 + rA) * K + kt + sAsw;
      llds16(g0, base + APL + (w * BM) * 16);
      if constexpr (BM == 128) {
        const u16* g1 = A1 + (size_t)(row0 + rA + 16) * K + kt + sAsw;
        llds16(g1, base + APL + (w * BM + 64) * 16);
      }
    }
#pragma unroll
    for (int it = 0; it < 4; ++it) {
      const int rowB = it * 32 + rB;
      const int slot = sB0 ^ (rowB & 7);   // inverse of read-side XOR swizzle
      const float* gp = Bf + (size_t)(col0 + rowB) * K + kt + slot * 4;
      llds16(gp, base + BOFF + it * 4096 + w * 1024);
    }
  };

  f32x4 acc[MF][4];
  const f32x4 zero = {0.f, 0.f, 0.f, 0.f};
#pragma unroll
  for (int m = 0; m < MF; ++m)
#pragma unroll
    for (int n = 0; n < 4; ++n) acc[m][n] = zero;

  stage(cu, 0);
  __syncthreads();

  for (int kt = 0;; kt += 32) {
    const bool more = (kt + 32 < K);
    if (more) stage(nx, kt + 32);   // prefetch overlaps this tile's compute

    const char* bufA = cu;
    const char* bufB = cu + BOFF;
    bf16x8 a0f[MF], bhf[4], blf[4];
#pragma unroll
    for (int m = 0; m < MF; ++m) {
      const int ar = wr * WRT + m * 16 + fr;
      a0f[m] = *reinterpret_cast<const bf16x8*>(
          bufA + ((ar * 64 + gq * 16) ^ ((ar & 3) << 4)));
    }
#pragma unroll
    for (int n = 0; n < 4; ++n) {
      const int rowB = wc * 64 + n * 16 + fr;
      const int bb = rowB * 128 + gq * 32;
      const int sw = (rowB & 7) << 4;
      f32x4 e0 = *reinterpret_cast<const f32x4*>(bufB + (bb ^ sw));
      f32x4 e1 = *reinterpret_cast<const f32x4*>(bufB + ((bb + 16) ^ sw));
      float e[8] = {e0[0], e0[1], e0[2], e0[3], e1[0], e1[1], e1[2], e1[3]};
      u32 hp[4], lp[4];
#pragma unroll
      for (int p = 0; p < 4; ++p) {
        const u32 u0 = __builtin_bit_cast(u32, e[2 * p]);
        const u32 u1 = __builtin_bit_cast(u32, e[2 * p + 1]);
        hp[p] = (u1 & 0xffff0000u) | (u0 >> 16);         // trunc-bf16 hi pair
        const float l0 = e[2 * p]     - __builtin_bit_cast(float, u0 & 0xffff0000u);
        const float l1 = e[2 * p + 1] - __builtin_bit_cast(float, u1 & 0xffff0000u);
        lp[p] = cvtpk_bf16(l0, l1);                      // RNE lo pair
      }
      u32x4 hv = {hp[0], hp[1], hp[2], hp[3]};
      u32x4 lv = {lp[0], lp[1], lp[2], lp[3]};
      bhf[n] = __builtin_bit_cast(bf16x8, hv);
      blf[n] = __builtin_bit_cast(bf16x8, lv);
    }
    if constexpr (MODE == 2) {
#pragma unroll
      for (int m = 0; m < MF; ++m)
#pragma unroll
        for (int n = 0; n < 4; ++n) {
          acc[m][n] = __builtin_amdgcn_mfma_f32_16x16x32_bf16(a0f[m], bhf[n], acc[m][n], 0, 0, 0);
          acc[m][n] = __builtin_amdgcn_mfma_f32_16x16x32_bf16(a0f[m], blf[n], acc[m][n], 0, 0, 0);
        }
    } else {
      bf16x8 a1f[MF];
#pragma unroll
      for (int m = 0; m < MF; ++m) {
        const int ar = wr * WRT + m * 16 + fr;
        a1f[m] = *reinterpret_cast<const bf16x8*>(
            cu + APL + ((ar * 64 + gq * 16) ^ ((ar & 3) << 4)));
      }
#pragma unroll
      for (int m = 0; m < MF; ++m)
#pragma unroll
        for (int n = 0; n < 4; ++n) {
          acc[m][n] = __builtin_amdgcn_mfma_f32_16x16x32_bf16(a0f[m], bhf[n], acc[m][n], 0, 0, 0);
          acc[m][n] = __builtin_amdgcn_mfma_f32_16x16x32_bf16(a1f[m], bhf[n], acc[m][n], 0, 0, 0);
          acc[m][n] = __builtin_amdgcn_mfma_f32_16x16x32_bf16(a0f[m], blf[n], acc[m][n], 0, 0, 0);
        }
    }
    if (!more) break;
    __syncthreads();   // drains prefetch vmcnt + this tile's readers
    char* t = cu; cu = nx; nx = t;
  }

  float sA = 1.0f, aQ = 1.0f;
  if constexpr (EPI == 1) { sA = (*sA_p) * (1.0f / 63.0f); aQ = *aQ_p; }
  if constexpr (EPI == 2 || EPI == 3) { sA = (*sA_p) * (1.0f / 63.0f); }
#pragma unroll
  for (int m = 0; m < MF; ++m)
#pragma unroll
    for (int n = 0; n < 4; ++n) {
      const int gcol = col0 + wc * 64 + n * 16 + fr;
#pragma unroll
      for (int j = 0; j < 4; ++j) {
        const int grow = row0 + wr * WRT + m * 16 + (lane >> 4) * 4 + j;
        const size_t idx = (size_t)grow * N + gcol;
        const float v = acc[m][n][j];
        if constexpr (EPI == 0) {
          Cf[idx] = auxf[idx] + v;
        } else if constexpr (EPI == 1) {
          float t = v * sA;
          float xd = fminf(fmaxf(t, 0.0f) / aQ, 1.0f);
          Cq[idx] = f2bf(rintf(xd * 63.0f));
        } else if constexpr (EPI == 2) {
          float t = v * sA;
          u16 h = f2bf(t);
          p_hi[idx] = h;
          p_lo[idx] = f2bf(t - bf2f(h));
        } else if constexpr (EPI == 3) {
          float gg = bf2f(p_hi[idx]) + bf2f(p_lo[idx]);
          float u = v * sA;
          float gu = (gg / (1.0f + expf(-gg))) * u;
          u16 h = f2bf(gu);
          p_hi[idx] = h;
          p_lo[idx] = f2bf(gu - bf2f(h));
        }
      }
    }
}

// ---------------------------------------------------------------------------
// V pre-transpose: vt[g][hs][t] = qkv[t][(g*6+5)*64 + hs]  (bf16 levels)
// ---------------------------------------------------------------------------
__global__ __launch_bounds__(256) void v_transpose(const u16* __restrict__ qkv,
                                                   u16* __restrict__ vt) {
  const int tb = blockIdx.x, g = blockIdx.y;
  const int vcol = (g * 6 + 5) * 64;
  __shared__ u16 t[64][72];
  const int tid = threadIdx.x;
#pragma unroll
  for (int i = 0; i < 2; ++i) {
    const int ch = i * 256 + tid;
    const int row = ch >> 3, c8 = (ch & 7) * 8;
    bf16x8 v = *reinterpret_cast<const bf16x8*>(
        qkv + (size_t)(tb * 64 + row) * QKV_DIM + vcol + c8);
#pragma unroll
    for (int j = 0; j < 8; ++j) t[c8 + j][row] = (u16)v[j];
  }
  __syncthreads();
#pragma unroll
  for (int i = 0; i < 2; ++i) {
    const int ch = i * 256 + tid;
    const int hs = ch >> 3, t8 = (ch & 7) * 8;
    ushort4 a, b;
    a.x = t[hs][t8];     a.y = t[hs][t8 + 1]; a.z = t[hs][t8 + 2]; a.w = t[hs][t8 + 3];
    b.x = t[hs][t8 + 4]; b.y = t[hs][t8 + 5]; b.z = t[hs][t8 + 6]; b.w = t[hs][t8 + 7];
    u16* dst = vt + (size_t)(g * 64 + hs) * T_SEQ + tb * 64 + t8;
    *reinterpret_cast<ushort4*>(dst) = a;
    *reinterpret_cast<ushort4*>(dst + 4) = b;
  }
}

// ---------------------------------------------------------------------------
// Fused MFMA attention (round-5 structure; + s_setprio around MFMA clusters).
// ---------------------------------------------------------------------------
__global__ __launch_bounds__(256) void attn_fused(const u16* __restrict__ qkv,
                                                  const u16* __restrict__ vt,
                                                  u16* __restrict__ y_hi,
                                                  u16* __restrict__ y_lo,
                                                  const float* __restrict__ aq_p,
                                                  const float* __restrict__ asm_p) {
  const int c = blockIdx.x;
  const int chi = c >> 8, mid = (c >> 4) & 15, clo = c & 15;
  const int h = mid + (chi << 4);
  const int qb = chi ? (15 - clo) : clo;
  const int g = h >> 2, s = h & 3;
  const int q_col = (g * 6 + s) * 64;
  const int k_col = (g * 6 + 4) * 64;

  __shared__ __align__(16) char lds_raw[49152];
  u16* Ks  = (u16*)(lds_raw + 16384);
  u16* Vts = (u16*)(lds_raw + 24576);

  const int tid = threadIdx.x;
  const int w = tid >> 6, lane = tid & 63;
  const int fr = lane & 15, gg = lane >> 4;
  char* myW = lds_raw + 32768 + w * 4096;

  const float sq = (*aq_p) * (1.0f / 63.0f);
  const float scale2 = sq * sq * 0.125f * LOG2E;
  const float alpha_sm = *asm_p;
  const float inv_a63 = 63.0f / alpha_sm;
  const float scale_y = (alpha_sm * (1.0f / 63.0f)) * sq;
  const int nkt = 2 * qb + 2;

#pragma unroll
  for (int i = 0; i < 4; ++i) {
    const int cb = (w * 4 + i) * 64;
    const int ch = cb + lane;
    const int row = ch >> 3;
    const int sb = ((ch & 7) * 16) ^ ((row & 7) << 4);
    llds16(qkv + (size_t)(qb * 128 + row) * QKV_DIM + q_col + (sb >> 1),
           lds_raw + cb * 16);
  }
  __syncthreads();
  bf16x8 qf[2][2];
#pragma unroll
  for (int nq = 0; nq < 2; ++nq)
#pragma unroll
    for (int ks = 0; ks < 2; ++ks) {
      const int qr = w * 32 + nq * 16 + fr;
      qf[nq][ks] = *reinterpret_cast<const bf16x8*>(
          lds_raw + ((qr * 128 + ks * 64 + gg * 16) ^ ((qr & 7) << 4)));
    }

  float m_run[2] = {-INFINITY, -INFINITY};
  float l_run[2] = {0.0f, 0.0f};

  for (int kt = 0; kt < nkt; ++kt) {
    __syncthreads();
#pragma unroll
    for (int i = 0; i < 2; ++i) {
      const int cb = (w * 2 + i) * 64;
      const int ch = cb + lane;
      const int row = ch >> 3;
      const int sb = ((ch & 7) * 16) ^ ((row & 7) << 4);
      llds16(qkv + (size_t)(kt * 64 + row) * QKV_DIM + k_col + (sb >> 1),
             (char*)Ks + cb * 16);
    }
    __syncthreads();
    f32x4 sac[4][2];
    const f32x4 zero = {0.f, 0.f, 0.f, 0.f};
#pragma unroll
    for (int mk = 0; mk < 4; ++mk)
#pragma unroll
      for (int nq = 0; nq < 2; ++nq) sac[mk][nq] = zero;
    __builtin_amdgcn_s_setprio(1);
#pragma unroll
    for (int ks = 0; ks < 2; ++ks)
#pragma unroll
      for (int mk = 0; mk < 4; ++mk) {
        const int kr = mk * 16 + fr;
        bf16x8 kf = *reinterpret_cast<const bf16x8*>(
            (char*)Ks + ((kr * 128 + ks * 64 + gg * 16) ^ ((kr & 7) << 4)));
#pragma unroll
        for (int nq = 0; nq < 2; ++nq)
          sac[mk][nq] = __builtin_amdgcn_mfma_f32_16x16x32_bf16(kf, qf[nq][ks], sac[mk][nq], 0, 0, 0);
      }
    __builtin_amdgcn_s_setprio(0);
    const bool edge = (kt >= 2 * qb);
#pragma unroll
    for (int nq = 0; nq < 2; ++nq) {
      const int qglob = qb * 128 + w * 32 + nq * 16 + fr;
      float tv[16];
#pragma unroll
      for (int mk = 0; mk < 4; ++mk)
#pragma unroll
        for (int jj = 0; jj < 4; ++jj) {
          float t = sac[mk][nq][jj] * scale2;
          if (edge && (kt * 64 + mk * 16 + gg * 4 + jj > qglob)) t = -INFINITY;
          tv[mk * 4 + jj] = t;
        }
      float vm = tv[0];
#pragma unroll
      for (int i = 1; i < 16; ++i) vm = fmaxf(vm, tv[i]);
      vm = fmaxf(vm, __shfl_xor(vm, 16));
      vm = fmaxf(vm, __shfl_xor(vm, 32));
      const float mn = fmaxf(m_run[nq], vm);
      float p = 0.0f;
#pragma unroll
      for (int i = 0; i < 16; ++i) p += exp2_hw(tv[i] - mn);
      p += __shfl_xor(p, 16);
      p += __shfl_xor(p, 32);
      l_run[nq] = l_run[nq] * exp2_hw(m_run[nq] - mn) + p;
      m_run[nq] = mn;
    }
  }

  const float linv[2] = {1.0f / l_run[0], 1.0f / l_run[1]};
  f32x4 oac[4][2];
  {
    const f32x4 zero = {0.f, 0.f, 0.f, 0.f};
#pragma unroll
    for (int mh = 0; mh < 4; ++mh)
#pragma unroll
      for (int nq = 0; nq < 2; ++nq) oac[mh][nq] = zero;
  }

  for (int kt = 0; kt < nkt; ++kt) {
    __syncthreads();
#pragma unroll
    for (int i = 0; i < 2; ++i) {
      const int cb = (w * 2 + i) * 64;
      const int ch = cb + lane;
      const int row = ch >> 3;
      const int sb = ((ch & 7) * 16) ^ ((row & 7) << 4);
      llds16(qkv + (size_t)(kt * 64 + row) * QKV_DIM + k_col + (sb >> 1),
             (char*)Ks + cb * 16);
      llds16(vt + (size_t)(g * 64 + row) * T_SEQ + kt * 64 + (sb >> 1),
             (char*)Vts + cb * 16);
    }
    __syncthreads();
    f32x4 sac[4][2];
    const f32x4 zero = {0.f, 0.f, 0.f, 0.f};
#pragma unroll
    for (int mk = 0; mk < 4; ++mk)
#pragma unroll
      for (int nq = 0; nq < 2; ++nq) sac[mk][nq] = zero;
    __builtin_amdgcn_s_setprio(1);
#pragma unroll
    for (int ks = 0; ks < 2; ++ks)
#pragma unroll
      for (int mk = 0; mk < 4; ++mk) {
        const int kr = mk * 16 + fr;
        bf16x8 kf = *reinterpret_cast<const bf16x8*>(
            (char*)Ks + ((kr * 128 + ks * 64 + gg * 16) ^ ((kr & 7) << 4)));
#pragma unroll
        for (int nq = 0; nq < 2; ++nq)
          sac[mk][nq] = __builtin_amdgcn_mfma_f32_16x16x32_bf16(kf, qf[nq][ks], sac[mk][nq], 0, 0, 0);
      }
    __builtin_amdgcn_s_setprio(0);
    const bool edge = (kt >= 2 * qb);
#pragma unroll
    for (int nq = 0; nq < 2; ++nq) {
      const int qglob = qb * 128 + w * 32 + nq * 16 + fr;
      const int qloc = nq * 16 + fr;
      const float mr = m_run[nq];
      const float cw = linv[nq] * inv_a63;
#pragma unroll
      for (int mk = 0; mk < 4; ++mk) {
        float lv[4];
#pragma unroll
        for (int jj = 0; jj < 4; ++jj) {
          float t = sac[mk][nq][jj] * scale2;
          if (edge && (kt * 64 + mk * 16 + gg * 4 + jj > qglob)) t = -INFINITY;
          lv[jj] = rintf(fminf(exp2_hw(t - mr) * cw, 63.0f));
        }
        const u32 pk0 = cvtpk_bf16(lv[0], lv[1]);
        const u32 pk1 = cvtpk_bf16(lv[2], lv[3]);
        const int b0 = (qloc * 128 + (mk * 16 + gg * 4) * 2) ^ ((qloc & 7) << 4);
        *reinterpret_cast<u32*>(myW + b0) = pk0;
        *reinterpret_cast<u32*>(myW + b0 + 4) = pk1;
      }
    }
    __builtin_amdgcn_s_setprio(1);
#pragma unroll
    for (int ks = 0; ks < 2; ++ks) {
      bf16x8 wf[2];
#pragma unroll
      for (int nq = 0; nq < 2; ++nq) {
        const int qloc = nq * 16 + fr;
        wf[nq] = *reinterpret_cast<const bf16x8*>(
            myW + ((qloc * 128 + ks * 64 + gg * 16) ^ ((qloc & 7) << 4)));
      }
#pragma unroll
      for (int mh = 0; mh < 4; ++mh) {
        const int hr = mh * 16 + fr;
        bf16x8 vf = *reinterpret_cast<const bf16x8*>(
            (char*)Vts + ((hr * 128 + ks * 64 + gg * 16) ^ ((hr & 7) << 4)));
#pragma unroll
        for (int nq = 0; nq < 2; ++nq)
          oac[mh][nq] = __builtin_amdgcn_mfma_f32_16x16x32_bf16(vf, wf[nq], oac[mh][nq], 0, 0, 0);
      }
    }
    __builtin_amdgcn_s_setprio(0);
  }

  __syncthreads();
  float* osc = (float*)(lds_raw + w * 8192);
#pragma unroll
  for (int mh = 0; mh < 4; ++mh)
#pragma unroll
    for (int nq = 0; nq < 2; ++nq) {
      const int qloc = nq * 16 + fr;
#pragma unroll
      for (int jj = 0; jj < 4; ++jj) {
        const int hs = mh * 16 + gg * 4 + jj;
        *reinterpret_cast<float*>(
            (char*)osc + ((qloc * 256 + hs * 4) ^ ((qloc & 7) << 4))) =
            oac[mh][nq][jj] * scale_y;
      }
    }
  __syncthreads();
  const int qp = lane >> 1, hf = lane & 1;
  const int qrow = qb * 128 + w * 32 + qp;
  u16* dh = y_hi + (size_t)qrow * C_DIM + h * 64 + hf * 32;
  u16* dl = y_lo + (size_t)qrow * C_DIM + h * 64 + hf * 32;
#pragma unroll
  for (int u = 0; u < 8; ++u) {
    f32x4 v = *reinterpret_cast<const f32x4*>(
        (char*)osc + ((qp * 256 + hf * 128 + u * 16) ^ ((qp & 7) << 4)));
    ushort4 hh, ll;
    u16 t0 = f2bf(v[0]); hh.x = t0; ll.x = f2bf(v[0] - bf2f(t0));
    u16 t1 = f2bf(v[1]); hh.y = t1; ll.y = f2bf(v[1] - bf2f(t1));
    u16 t2 = f2bf(v[2]); hh.z = t2; ll.z = f2bf(v[2] - bf2f(t2));
    u16 t3 = f2bf(v[3]); hh.w = t3; ll.w = f2bf(v[3] - bf2f(t3));
    *reinterpret_cast<ushort4*>(dh + u * 4) = hh;
    *reinterpret_cast<ushort4*>(dl + u * 4) = ll;
  }
}

// ---------------------------------------------------------------------------
extern "C" void kernel_launch(void* const* d_in, const int* in_sizes, int n_in,
                              void* d_out, int out_size, void* d_ws, size_t ws_size,
                              hipStream_t stream) {
  (void)in_sizes; (void)n_in; (void)out_size; (void)ws_size;
  const float* x      = (const float*)d_in[0];
  const float* w1     = (const float*)d_in[1];
  const float* w2     = (const float*)d_in[2];
  const float* a1     = (const float*)d_in[3];
  const float* a2     = (const float*)d_in[4];
  const float* aq     = (const float*)d_in[5];
  const float* a_sm   = (const float*)d_in[6];
  const float* attn_w = (const float*)d_in[7];
  const float* proj_w = (const float*)d_in[8];
  const float* fc1_w  = (const float*)d_in[9];
  const float* fc2_w  = (const float*)d_in[10];
  const float* mlp_w  = (const float*)d_in[11];
  float* out = (float*)d_out;

  // Workspace (bytes), total 54,525,952 (52 MiB):
  //   [0, 8388608)       nb: n1/n2 integer levels (bf16)
  //   R = [8388608, ...) phase A: qkv_i(12.6M) | y_hi(8.4M) | y_lo(8.4M) | vt(2M)
  //                      phase B (after proj): ghi(23.1M) | glo(23.1M)
  char* ws = (char*)d_ws;
  u16* nb    = (u16*)ws;
  char* R    = ws + 8388608;
  u16* qkv_i = (u16*)R;
  u16* y_hi  = (u16*)(R + 12582912);
  u16* y_lo  = (u16*)(R + 20971520);
  u16* vt    = (u16*)(R + 29360128);
  u16* ghi   = (u16*)R;
  u16* glo   = (u16*)(R + 23068672);

  // 1) n1 levels
  rmsnorm_quant_int<<<T_SEQ, 256, 0, stream>>>(x, w1, a1, nb);
  // 2) qkv = quant levels of (n1 @ attn_w^T)   (BM=64: 768 blocks = 3/CU)
  gemm_mfma<2, 1, 64><<<dim3(QKV_DIM / 128, T_SEQ / 64), 256, 0, stream>>>(
      nb, nullptr, attn_w, nullptr, qkv_i, nullptr, nullptr, nullptr,
      a1, aq, T_SEQ, QKV_DIM, C_DIM);
  // 3) attention (MFMA)
  v_transpose<<<dim3(32, 8), 256, 0, stream>>>(qkv_i, vt);
  attn_fused<<<512, 256, 0, stream>>>(qkv_i, vt, y_hi, y_lo, aq, a_sm);
  // 4) x2 = x + y @ proj_w^T   (BM=64: 512 blocks = 2/CU)
  gemm_mfma<3, 0, 64><<<dim3(C_DIM / 128, T_SEQ / 64), 256, 0, stream>>>(
      y_hi, y_lo, proj_w, out, nullptr, x, nullptr, nullptr,
      nullptr, nullptr, T_SEQ, C_DIM, C_DIM);
  // 5) n2 levels
  rmsnorm_quant_int<<<T_SEQ, 256, 0, stream>>>(out, w2, a2, nb);
  // 6) g = n2 @ fc1_w^T  (BM=128: 704 blocks, already well-occupied)
  gemm_mfma<2, 2, 128><<<dim3(FF_DIM / 128, T_SEQ / 128), 256, 0, stream>>>(
      nb, nullptr, fc1_w, nullptr, nullptr, nullptr, ghi, glo,
      a2, nullptr, T_SEQ, FF_DIM, C_DIM);
  // 7) gu = silu(g) * (n2 @ fc2_w^T)  (in place over g planes)
  gemm_mfma<2, 3, 128><<<dim3(FF_DIM / 128, T_SEQ / 128), 256, 0, stream>>>(
      nb, nullptr, fc2_w, nullptr, nullptr, nullptr, ghi, glo,
      a2, nullptr, T_SEQ, FF_DIM, C_DIM);
  // 8) out = x2 + gu @ mlp_proj_w^T   (K = FF; BM=64: 512 blocks = 2/CU)
  gemm_mfma<3, 0, 64><<<dim3(C_DIM / 128, T_SEQ / 64), 256, 0, stream>>>(
      ghi, glo, mlp_w, out, nullptr, out, nullptr, nullptr,
      nullptr, nullptr, T_SEQ, C_DIM, FF_DIM);
}